// Round 9
// baseline (317.541 us; speedup 1.0000x reference)
//
#include <hip/hip_runtime.h>
#include <hip/hip_bf16.h>
#include <math.h>

typedef __bf16 bf16_t;
typedef __bf16 bf16x8 __attribute__((ext_vector_type(8)));
typedef __bf16 bf16x4 __attribute__((ext_vector_type(4)));
typedef float  f32x4  __attribute__((ext_vector_type(4)));

#define L_DIM 2048
#define D_DIM 1024
#define H_DIM 16
#define M_DIM 4096
#define KTOP 409
#define SLOTS 448    // 7 * 64, padded (sel = -1 beyond KTOP)
#define KSPLIT 8
#define KCHUNK 256   // L_DIM / KSPLIT

// split f32 into bf16 hi + bf16 lo (a ~= hi + lo)
__device__ __forceinline__ void split2(float a, bf16_t& h, bf16_t& l) {
  h = (bf16_t)a;
  l = (bf16_t)(a - (float)h);
}

// async global -> LDS, 16B per lane; lds ptr must be wave-uniform (m104/m108)
__device__ __forceinline__ void gld16(const bf16_t* g, bf16_t* l) {
  __builtin_amdgcn_global_load_lds(
      (const __attribute__((address_space(1))) void*)g,
      (__attribute__((address_space(3))) void*)l, 16, 0, 0);
}

// stage a 128x32 bf16 tile (row stride D_DIM) into unpadded LDS.
#define STAGE_TILE128(src, dst)                                               \
  {                                                                           \
    const int seg0 = wave * 2;                                                \
    const int r0 = seg0 * 16 + (lane >> 2);                                   \
    const int c0 = (lane & 3) * 8;                                            \
    gld16((src) + (size_t)r0 * D_DIM + c0, (dst) + seg0 * 512);               \
    gld16((src) + (size_t)(r0 + 16) * D_DIM + c0, (dst) + (seg0 + 1) * 512);  \
  }

// stage a 64x32 bf16 tile: one 16-row segment per wave.
#define STAGE_TILE64(src, dst)                                                \
  {                                                                           \
    const int r0 = wave * 16 + (lane >> 2);                                   \
    const int c0 = (lane & 3) * 8;                                            \
    gld16((src) + (size_t)r0 * D_DIM + c0, (dst) + wave * 512);               \
  }

// ---------------------------------------------------------------------------
// prep: pre-split x and Wq into bf16 hi/lo; pre-round Wk/Wv/Wo to bf16.
// ---------------------------------------------------------------------------
__global__ __launch_bounds__(256) void prep_kernel(
    const float* __restrict__ x,  const float* __restrict__ Wq,
    const float* __restrict__ Wk, const float* __restrict__ Wv,
    const float* __restrict__ Wo,
    bf16_t* __restrict__ xhi, bf16_t* __restrict__ xlo,
    bf16_t* __restrict__ Wqhi, bf16_t* __restrict__ Wqlo,
    bf16_t* __restrict__ Wkb,  bf16_t* __restrict__ Wvb,
    bf16_t* __restrict__ Wob)
{
  const int XV = (M_DIM * D_DIM) / 4;
  const int WV = (D_DIM * D_DIM) / 4;
  int i = blockIdx.x * 256 + threadIdx.x;
  if (i < XV) {
    f32x4 v = ((const f32x4*)x)[i];
    bf16x4 h, l;
    #pragma unroll
    for (int j = 0; j < 4; ++j) { bf16_t hh, ll; split2(v[j], hh, ll); h[j] = hh; l[j] = ll; }
    ((bf16x4*)xhi)[i] = h;
    ((bf16x4*)xlo)[i] = l;
  } else if (i < XV + WV) {
    int j0 = i - XV;
    f32x4 v = ((const f32x4*)Wq)[j0];
    bf16x4 h, l;
    #pragma unroll
    for (int j = 0; j < 4; ++j) { bf16_t hh, ll; split2(v[j], hh, ll); h[j] = hh; l[j] = ll; }
    ((bf16x4*)Wqhi)[j0] = h;
    ((bf16x4*)Wqlo)[j0] = l;
  } else if (i < XV + 2 * WV) {
    int j0 = i - XV - WV;
    f32x4 v = ((const f32x4*)Wk)[j0];
    bf16x4 h;
    #pragma unroll
    for (int j = 0; j < 4; ++j) h[j] = (bf16_t)v[j];
    ((bf16x4*)Wkb)[j0] = h;
  } else if (i < XV + 3 * WV) {
    int j0 = i - XV - 2 * WV;
    f32x4 v = ((const f32x4*)Wv)[j0];
    bf16x4 h;
    #pragma unroll
    for (int j = 0; j < 4; ++j) h[j] = (bf16_t)v[j];
    ((bf16x4*)Wvb)[j0] = h;
  } else {
    int j0 = i - XV - 3 * WV;
    f32x4 v = ((const f32x4*)Wo)[j0];
    bf16x4 h;
    #pragma unroll
    for (int j = 0; j < 4; ++j) h[j] = (bf16_t)v[j];
    ((bf16x4*)Wob)[j0] = h;
  }
}

// ---------------------------------------------------------------------------
// Fused QKV projections, async staging (round-6 structure, best measured).
// z=0: Q 128x128 split-bf16 3-product + f32 norms; z=1: K; z=2: V transposed.
// ---------------------------------------------------------------------------
__global__ __launch_bounds__(256) void gemm_qkv(
    const bf16_t* __restrict__ xhi, const bf16_t* __restrict__ xlo,
    const bf16_t* __restrict__ Wqhi, const bf16_t* __restrict__ Wqlo,
    const bf16_t* __restrict__ Wkb, const bf16_t* __restrict__ Wvb,
    const float* __restrict__ bq, const float* __restrict__ bk, const float* __restrict__ bv,
    bf16_t* __restrict__ Qhi, bf16_t* __restrict__ Khi, bf16_t* __restrict__ VThi,
    float* __restrict__ norms)
{
  const int z = blockIdx.z;
  const int n0   = blockIdx.x * 128;
  const int row0 = blockIdx.y * 128;

  __shared__ __align__(16) bf16_t sm[4][4096];

  const int tid  = threadIdx.x;
  const int lane = tid & 63;
  const int wave = tid >> 6;
  const int wr = wave >> 1, wc = wave & 1;
  const int lm = lane & 15, quad = lane >> 4;

  const f32x4 vzero = {0.f, 0.f, 0.f, 0.f};
  f32x4 acc[4][4];
  #pragma unroll
  for (int mi = 0; mi < 4; ++mi)
    #pragma unroll
    for (int ni = 0; ni < 4; ++ni) acc[mi][ni] = vzero;

  if (z == 0) {
    for (int k0 = 0; k0 < D_DIM; k0 += 32) {
      __syncthreads();
      STAGE_TILE128(xhi  + (size_t)row0 * D_DIM + k0, sm[0]);
      STAGE_TILE128(xlo  + (size_t)row0 * D_DIM + k0, sm[1]);
      STAGE_TILE128(Wqhi + (size_t)n0   * D_DIM + k0, sm[2]);
      STAGE_TILE128(Wqlo + (size_t)n0   * D_DIM + k0, sm[3]);
      __syncthreads();
      bf16x8 afh[4], afl[4], bfh[4], bfl[4];
      #pragma unroll
      for (int mi = 0; mi < 4; ++mi) {
        afh[mi] = *reinterpret_cast<const bf16x8*>(&sm[0][(wr * 64 + mi * 16 + lm) * 32 + quad * 8]);
        afl[mi] = *reinterpret_cast<const bf16x8*>(&sm[1][(wr * 64 + mi * 16 + lm) * 32 + quad * 8]);
      }
      #pragma unroll
      for (int ni = 0; ni < 4; ++ni) {
        bfh[ni] = *reinterpret_cast<const bf16x8*>(&sm[2][(wc * 64 + ni * 16 + lm) * 32 + quad * 8]);
        bfl[ni] = *reinterpret_cast<const bf16x8*>(&sm[3][(wc * 64 + ni * 16 + lm) * 32 + quad * 8]);
      }
      #pragma unroll
      for (int mi = 0; mi < 4; ++mi)
        #pragma unroll
        for (int ni = 0; ni < 4; ++ni) {
          acc[mi][ni] = __builtin_amdgcn_mfma_f32_16x16x32_bf16(afh[mi], bfh[ni], acc[mi][ni], 0, 0, 0);
          acc[mi][ni] = __builtin_amdgcn_mfma_f32_16x16x32_bf16(afh[mi], bfl[ni], acc[mi][ni], 0, 0, 0);
          acc[mi][ni] = __builtin_amdgcn_mfma_f32_16x16x32_bf16(afl[mi], bfh[ni], acc[mi][ni], 0, 0, 0);
        }
    }

    float bvv[4];
    #pragma unroll
    for (int ni = 0; ni < 4; ++ni) bvv[ni] = bq[n0 + wc * 64 + ni * 16 + lm];
    #pragma unroll
    for (int mi = 0; mi < 4; ++mi)
      #pragma unroll
      for (int ni = 0; ni < 4; ++ni)
        #pragma unroll
        for (int r = 0; r < 4; ++r) acc[mi][ni][r] += bvv[ni];

    const int h = (n0 + wc * 64) >> 6;
    #pragma unroll
    for (int mi = 0; mi < 4; ++mi)
      #pragma unroll
      for (int r = 0; r < 4; ++r) {
        float s = 0.f;
        #pragma unroll
        for (int ni = 0; ni < 4; ++ni) { float v = acc[mi][ni][r]; s += v * v; }
        s += __shfl_xor(s, 1); s += __shfl_xor(s, 2);
        s += __shfl_xor(s, 4); s += __shfl_xor(s, 8);
        if (lm == 0) {
          int row = row0 + wr * 64 + mi * 16 + quad * 4 + r;
          int bb = row >> 11, ll = row & (L_DIM - 1);
          norms[(bb * H_DIM + h) * L_DIM + ll] = s;
        }
      }

    #pragma unroll
    for (int mi = 0; mi < 4; ++mi)
      #pragma unroll
      for (int r = 0; r < 4; ++r) {
        int row = row0 + wr * 64 + mi * 16 + quad * 4 + r;
        #pragma unroll
        for (int ni = 0; ni < 4; ++ni)
          Qhi[(size_t)row * D_DIM + n0 + wc * 64 + ni * 16 + lm] = (bf16_t)acc[mi][ni][r];
      }
  } else {
    const bf16_t* W = (z == 1) ? Wkb : Wvb;
    for (int k0 = 0; k0 < D_DIM; k0 += 32) {
      __syncthreads();
      STAGE_TILE128(xhi + (size_t)row0 * D_DIM + k0, sm[0]);
      STAGE_TILE128(W   + (size_t)n0   * D_DIM + k0, sm[2]);
      __syncthreads();
      bf16x8 af[4], bfr[4];
      #pragma unroll
      for (int mi = 0; mi < 4; ++mi)
        af[mi] = *reinterpret_cast<const bf16x8*>(&sm[0][(wr * 64 + mi * 16 + lm) * 32 + quad * 8]);
      #pragma unroll
      for (int ni = 0; ni < 4; ++ni)
        bfr[ni] = *reinterpret_cast<const bf16x8*>(&sm[2][(wc * 64 + ni * 16 + lm) * 32 + quad * 8]);
      #pragma unroll
      for (int mi = 0; mi < 4; ++mi)
        #pragma unroll
        for (int ni = 0; ni < 4; ++ni)
          acc[mi][ni] = __builtin_amdgcn_mfma_f32_16x16x32_bf16(af[mi], bfr[ni], acc[mi][ni], 0, 0, 0);
    }

    const float* bias = (z == 1) ? bk : bv;
    float bvv[4];
    #pragma unroll
    for (int ni = 0; ni < 4; ++ni) bvv[ni] = bias[n0 + wc * 64 + ni * 16 + lm];
    #pragma unroll
    for (int mi = 0; mi < 4; ++mi)
      #pragma unroll
      for (int ni = 0; ni < 4; ++ni)
        #pragma unroll
        for (int r = 0; r < 4; ++r) acc[mi][ni][r] += bvv[ni];

    if (z == 1) {
      #pragma unroll
      for (int mi = 0; mi < 4; ++mi)
        #pragma unroll
        for (int r = 0; r < 4; ++r) {
          int row = row0 + wr * 64 + mi * 16 + quad * 4 + r;
          #pragma unroll
          for (int ni = 0; ni < 4; ++ni)
            Khi[(size_t)row * D_DIM + n0 + wc * 64 + ni * 16 + lm] = (bf16_t)acc[mi][ni][r];
        }
    } else {
      #pragma unroll
      for (int mi = 0; mi < 4; ++mi) {
        int rbase = row0 + wr * 64 + mi * 16 + quad * 4;
        int bb = rbase >> 11, l0 = rbase & (L_DIM - 1);
        #pragma unroll
        for (int ni = 0; ni < 4; ++ni) {
          int col = n0 + wc * 64 + ni * 16 + lm;
          bf16x4 wv;
          #pragma unroll
          for (int r = 0; r < 4; ++r) wv[r] = (bf16_t)acc[mi][ni][r];
          *reinterpret_cast<bf16x4*>(&VThi[((size_t)(bb * D_DIM + col)) * L_DIM + l0]) = wv;
        }
      }
    }
  }
}

// ---------------------------------------------------------------------------
// Output projection: 64x128 tiles, grid (8,64) = 2 blocks/CU.
// ---------------------------------------------------------------------------
__global__ __launch_bounds__(256) void gemm_out(
    const bf16_t* __restrict__ Ahi, const bf16_t* __restrict__ Wob,
    const float* __restrict__ bias, float* __restrict__ C)
{
  const int n0   = blockIdx.x * 128;
  const int row0 = blockIdx.y * 64;

  __shared__ __align__(16) bf16_t sm[6144];

  const int tid  = threadIdx.x;
  const int lane = tid & 63;
  const int wave = tid >> 6;
  const int wr = wave >> 1, wc = wave & 1;
  const int lm = lane & 15, quad = lane >> 4;

  bf16_t* sA = sm;
  bf16_t* sB = sm + 2048;

  const f32x4 vzero = {0.f, 0.f, 0.f, 0.f};
  f32x4 acc[2][4];
  #pragma unroll
  for (int mi = 0; mi < 2; ++mi)
    #pragma unroll
    for (int ni = 0; ni < 4; ++ni) acc[mi][ni] = vzero;

  for (int k0 = 0; k0 < D_DIM; k0 += 32) {
    __syncthreads();
    STAGE_TILE64(Ahi + (size_t)row0 * D_DIM + k0, sA);
    STAGE_TILE128(Wob + (size_t)n0 * D_DIM + k0, sB);
    __syncthreads();
    bf16x8 af[2], bfr[4];
    #pragma unroll
    for (int mi = 0; mi < 2; ++mi)
      af[mi] = *reinterpret_cast<const bf16x8*>(&sA[(wr * 32 + mi * 16 + lm) * 32 + quad * 8]);
    #pragma unroll
    for (int ni = 0; ni < 4; ++ni)
      bfr[ni] = *reinterpret_cast<const bf16x8*>(&sB[(wc * 64 + ni * 16 + lm) * 32 + quad * 8]);
    #pragma unroll
    for (int mi = 0; mi < 2; ++mi)
      #pragma unroll
      for (int ni = 0; ni < 4; ++ni)
        acc[mi][ni] = __builtin_amdgcn_mfma_f32_16x16x32_bf16(af[mi], bfr[ni], acc[mi][ni], 0, 0, 0);
  }

  float bvv[4];
  #pragma unroll
  for (int ni = 0; ni < 4; ++ni) bvv[ni] = bias[n0 + wc * 64 + ni * 16 + lm];
  #pragma unroll
  for (int mi = 0; mi < 2; ++mi)
    #pragma unroll
    for (int r = 0; r < 4; ++r) {
      int row = row0 + wr * 32 + mi * 16 + quad * 4 + r;
      #pragma unroll
      for (int ni = 0; ni < 4; ++ni)
        C[(size_t)row * D_DIM + n0 + wc * 64 + ni * 16 + lm] = acc[mi][ni][r] + bvv[ni];
    }
}

// ---------------------------------------------------------------------------
// Exact top-409 per (b,h) via 4-pass radix select on positive-f32 bit order.
// Same SET as lax.top_k (boundary ties -> smallest indices, via eq-bitmask
// popcount ranks). ~14 barriers vs 66 for bitonic. Emits compact sel list
// (order-free) + slotmap inverse map.
// ---------------------------------------------------------------------------
__global__ __launch_bounds__(256) void topk_kernel(
    const float* __restrict__ norms, int* __restrict__ sel, int* __restrict__ slotmap)
{
  const int bh = blockIdx.x;
  __shared__ unsigned int vals[L_DIM];       // 8 KB
  __shared__ int hist[256];
  __shared__ unsigned int eqmask[L_DIM / 32];
  __shared__ int s_need, s_bin, cnt_gt;
  const int t = threadIdx.x;

  for (int i = t; i < L_DIM; i += 256) {
    vals[i] = __float_as_uint(norms[bh * L_DIM + i]);   // norms >= 0
    slotmap[bh * L_DIM + i] = -1;
  }

  unsigned int prefix = 0, pmask = 0;
  int need = KTOP;
  #pragma unroll
  for (int p = 24; p >= 0; p -= 8) {
    hist[t & 255] = 0;                       // 256 threads cover 256 bins
    __syncthreads();
    for (int i = t; i < L_DIM; i += 256) {
      unsigned int v = vals[i];
      if ((v & pmask) == prefix) atomicAdd(&hist[(v >> p) & 255], 1);
    }
    __syncthreads();
    if (t == 0) {
      int cum = 0, B = 0;
      for (int b2 = 255; b2 >= 0; --b2) {
        if (cum + hist[b2] >= need) { B = b2; break; }
        cum += hist[b2];
      }
      s_need = need - cum;
      s_bin = B;
    }
    __syncthreads();
    need = s_need;
    prefix |= ((unsigned int)s_bin) << p;
    pmask |= (0xFFu << p);
  }
  // threshold T = prefix; take all v > T, plus `need` of v == T by smallest idx

  if (t == 0) cnt_gt = 0;
  for (int i = t; i < L_DIM / 32; i += 256) eqmask[i] = 0;
  __syncthreads();
  for (int i = t; i < L_DIM; i += 256) {
    unsigned int v = vals[i];
    if (v > prefix) {
      int pos = atomicAdd(&cnt_gt, 1);
      sel[bh * SLOTS + pos] = i;
      slotmap[bh * L_DIM + i] = pos;
    } else if (v == prefix) {
      atomicOr(&eqmask[i >> 5], 1u << (i & 31));
    }
  }
  __syncthreads();
  const int base = cnt_gt;                   // == KTOP - need by construction
  for (int i = t; i < L_DIM; i += 256) {
    if (vals[i] == prefix) {
      int w = i >> 5, rank = 0;
      for (int ww = 0; ww < w; ++ww) rank += __popc(eqmask[ww]);
      rank += __popc(eqmask[w] & ((1u << (i & 31)) - 1u));
      if (rank < need) {
        int pos = base + rank;
        sel[bh * SLOTS + pos] = i;
        slotmap[bh * L_DIM + i] = pos;
      }
    }
  }
  for (int i = t; i < SLOTS; i += 256)
    if (i >= KTOP) sel[bh * SLOTS + i] = -1;
}

// ---------------------------------------------------------------------------
// K-split flash attention, single-bf16 Q/K/V (unchanged from round 8).
// ---------------------------------------------------------------------------
__global__ __launch_bounds__(256) void attn_kernel(
    const bf16_t* __restrict__ Qhi,
    const bf16_t* __restrict__ Khi,
    const bf16_t* __restrict__ VThi,
    const int* __restrict__ sel,
    float* __restrict__ Ol, bf16_t* __restrict__ Oo)
{
  const int bx = blockIdx.x;
  const int bh = bx & 31;
  const int t2 = bx >> 5;
  const int qc = t2 % 7;
  const int ks = t2 / 7;
  const int b = bh >> 4, h = bh & 15;
  const int wave = threadIdx.x >> 6;
  const int lane = threadIdx.x & 63;
  const int lm = lane & 15, quad = lane >> 4;

  __shared__ __align__(16) bf16_t sPh[4][16][40];

  const int qbase = qc * 64 + wave * 16;
  const int qi = sel[bh * SLOTS + qbase + lm];
  const size_t qo = ((size_t)(b * L_DIM + (qi >= 0 ? qi : 0))) * D_DIM + h * 64;
  const bf16x8 qa0 = *reinterpret_cast<const bf16x8*>(&Qhi[qo + quad * 8]);
  const bf16x8 qa1 = *reinterpret_cast<const bf16x8*>(&Qhi[qo + 32 + quad * 8]);

  const f32x4 vzero = {0.f, 0.f, 0.f, 0.f};
  float l_l[4] = {0.f, 0.f, 0.f, 0.f};
  f32x4 o[4];
  #pragma unroll
  for (int ni = 0; ni < 4; ++ni) o[ni] = vzero;

  const float scale = 0.125f;
  const size_t kbase = (size_t)(b * L_DIM) * D_DIM + h * 64;
  const int key0 = ks * KCHUNK;

  for (int kt = 0; kt < KCHUNK; kt += 32) {
    size_t kr0 = kbase + (size_t)(key0 + kt + lm) * D_DIM;
    size_t kr1 = kbase + (size_t)(key0 + kt + 16 + lm) * D_DIM;
    bf16x8 kb0 = *reinterpret_cast<const bf16x8*>(&Khi[kr0 + quad * 8]);
    bf16x8 kb1 = *reinterpret_cast<const bf16x8*>(&Khi[kr0 + 32 + quad * 8]);
    bf16x8 kb2 = *reinterpret_cast<const bf16x8*>(&Khi[kr1 + quad * 8]);
    bf16x8 kb3 = *reinterpret_cast<const bf16x8*>(&Khi[kr1 + 32 + quad * 8]);
    bf16x8 vbh[4];
    #pragma unroll
    for (int ni = 0; ni < 4; ++ni) {
      size_t vo = ((size_t)(b * D_DIM + h * 64 + ni * 16 + lm)) * L_DIM + key0 + kt + quad * 8;
      vbh[ni] = *reinterpret_cast<const bf16x8*>(&VThi[vo]);
    }
    f32x4 s0 = vzero, s1 = vzero;
    s0 = __builtin_amdgcn_mfma_f32_16x16x32_bf16(qa0, kb0, s0, 0, 0, 0);
    s0 = __builtin_amdgcn_mfma_f32_16x16x32_bf16(qa1, kb1, s0, 0, 0, 0);
    s1 = __builtin_amdgcn_mfma_f32_16x16x32_bf16(qa0, kb2, s1, 0, 0, 0);
    s1 = __builtin_amdgcn_mfma_f32_16x16x32_bf16(qa1, kb3, s1, 0, 0, 0);
    #pragma unroll
    for (int r = 0; r < 4; ++r) {
      float p0 = __expf(s0[r] * scale);
      float p1 = __expf(s1[r] * scale);
      l_l[r] += p0 + p1;
      sPh[wave][quad * 4 + r][lm]      = (bf16_t)p0;
      sPh[wave][quad * 4 + r][16 + lm] = (bf16_t)p1;
    }
    bf16x8 pah = *reinterpret_cast<const bf16x8*>(&sPh[wave][lm][quad * 8]);
    #pragma unroll
    for (int ni = 0; ni < 4; ++ni)
      o[ni] = __builtin_amdgcn_mfma_f32_16x16x32_bf16(pah, vbh[ni], o[ni], 0, 0, 0);
  }

  #pragma unroll
  for (int r = 0; r < 4; ++r) {
    l_l[r] += __shfl_xor(l_l[r], 1);
    l_l[r] += __shfl_xor(l_l[r], 2);
    l_l[r] += __shfl_xor(l_l[r], 4);
    l_l[r] += __shfl_xor(l_l[r], 8);
  }

  #pragma unroll
  for (int r = 0; r < 4; ++r) {
    int slot = qbase + quad * 4 + r;
    int s2 = sel[bh * SLOTS + slot];
    if (s2 >= 0) {
      size_t gs = (size_t)(bh * SLOTS + slot) * KSPLIT + ks;
      if (lm == 0) Ol[gs] = l_l[r];
      #pragma unroll
      for (int ni = 0; ni < 4; ++ni)
        Oo[gs * 64 + ni * 16 + lm] = (bf16_t)o[ni][r];
    }
  }
}

// ---------------------------------------------------------------------------
// finish: each AO row written exactly once. Selected rows (via slotmap) get
// combined k-split partials; others get mean(V). Wave = one row -> uniform.
// ---------------------------------------------------------------------------
__global__ __launch_bounds__(256) void finish_kernel(
    const bf16_t* __restrict__ VThi,
    const float* __restrict__ Ol, const bf16_t* __restrict__ Oo,
    const int* __restrict__ slotmap, bf16_t* __restrict__ AOhi)
{
  const int bh = blockIdx.x;
  const int b = bh >> 4, h = bh & 15;
  const int t = threadIdx.x;
  __shared__ float smean[64];
  {
    const int hd = t >> 2, part = t & 3;
    size_t base = ((size_t)(b * D_DIM + h * 64 + hd)) * L_DIM;
    float s = 0.f;
    for (int l0 = part * 512; l0 < part * 512 + 512; l0 += 8) {
      bf16x8 vh = *reinterpret_cast<const bf16x8*>(&VThi[base + l0]);
      #pragma unroll
      for (int j = 0; j < 8; ++j) s += (float)vh[j];
    }
    s += __shfl_xor(s, 1);
    s += __shfl_xor(s, 2);
    if (part == 0) smean[hd] = s * (1.0f / (float)L_DIM);
  }
  __syncthreads();
  const int lbase = blockIdx.y * 256;
  for (int i = t; i < 256 * 64; i += 256) {
    int l = lbase + (i >> 6), hd = i & 63;
    int slot = slotmap[bh * L_DIM + l];       // wave-uniform (64 lanes = 1 row)
    float val;
    if (slot < 0) {
      val = smean[hd];
    } else {
      size_t gs = (size_t)(bh * SLOTS + slot) * KSPLIT;
      float L = 0.f, ov = 0.f;
      #pragma unroll
      for (int s = 0; s < KSPLIT; ++s) {
        L  += Ol[gs + s];
        ov += (float)Oo[(gs + s) * 64 + hd];
      }
      val = ov / L;
    }
    AOhi[((size_t)(b * L_DIM + l)) * D_DIM + h * 64 + hd] = (bf16_t)val;
  }
}

// ---------------------------------------------------------------------------
extern "C" void kernel_launch(void* const* d_in, const int* in_sizes, int n_in,
                              void* d_out, int out_size, void* d_ws, size_t ws_size,
                              hipStream_t stream) {
  const float* x  = (const float*)d_in[0];
  const float* Wq = (const float*)d_in[1];
  const float* bq = (const float*)d_in[2];
  const float* Wk = (const float*)d_in[3];
  const float* bk = (const float*)d_in[4];
  const float* Wv = (const float*)d_in[5];
  const float* bv = (const float*)d_in[6];
  const float* Wo = (const float*)d_in[7];
  const float* bo = (const float*)d_in[8];
  float* out = (float*)d_out;

  // ws layout (~43.3 MB):
  //  [0,8)    Qhi  (aliased as AOhi after attn)
  //  [8,16)   VThi
  //  [16,24)  xhi  -+ dead after gemm_qkv; [16,32) reused for Oo (bf16, 14.7MB)
  //  [24,32)  xlo  -+
  //  [32,34)  Wqhi  [34,36) Wqlo  [36,38) Wkb  [38,40) Wvb  [40,42) Wob
  //  42MB: norms (256K) | +320K: sel (64K) | +384K: Ol (448K) | +832K: slotmap (256K)
  // Khi lives in d_out (8 of 16 MB) — dead until gemm_out rewrites d_out.
  const size_t MB = 1u << 20;
  const size_t KB = 1u << 10;
  char* ws = (char*)d_ws;
  bf16_t* Qhi  = (bf16_t*)(ws);
  bf16_t* VThi = (bf16_t*)(ws + 8 * MB);
  bf16_t* xhi  = (bf16_t*)(ws + 16 * MB);
  bf16_t* xlo  = (bf16_t*)(ws + 24 * MB);
  bf16_t* Oo   = (bf16_t*)(ws + 16 * MB);         // aliases xhi/xlo
  bf16_t* Wqhi = (bf16_t*)(ws + 32 * MB);
  bf16_t* Wqlo = (bf16_t*)(ws + 34 * MB);
  bf16_t* Wkb  = (bf16_t*)(ws + 36 * MB);
  bf16_t* Wvb  = (bf16_t*)(ws + 38 * MB);
  bf16_t* Wob  = (bf16_t*)(ws + 40 * MB);
  float*  norms   = (float*)(ws + 42 * MB);
  int*    sel     = (int*)(ws + 42 * MB + 320 * KB);
  float*  Ol      = (float*)(ws + 42 * MB + 384 * KB);
  int*    slotmap = (int*)(ws + 42 * MB + 832 * KB);
  bf16_t* AOhi = Qhi;
  bf16_t* Khi = (bf16_t*)d_out;

  dim3 blk(256);
  prep_kernel<<<dim3(8192), blk, 0, stream>>>(x, Wq, Wk, Wv, Wo,
                                              xhi, xlo, Wqhi, Wqlo, Wkb, Wvb, Wob);
  gemm_qkv<<<dim3(8, 32, 3), blk, 0, stream>>>(xhi, xlo, Wqhi, Wqlo, Wkb, Wvb,
                                               bq, bk, bv, Qhi, Khi, VThi, norms);
  topk_kernel<<<dim3(32), blk, 0, stream>>>(norms, sel, slotmap);
  attn_kernel<<<dim3(32 * 7 * KSPLIT), blk, 0, stream>>>(Qhi, Khi, VThi, sel, Ol, Oo);
  finish_kernel<<<dim3(32, 8), blk, 0, stream>>>(VThi, Ol, Oo, slotmap, AOhi);
  gemm_out<<<dim3(8, 64), blk, 0, stream>>>(AOhi, Wob, bo, out);
}